// Round 16
// baseline (84.879 us; speedup 1.0000x reference)
//
#include <hip/hip_runtime.h>

// Problem constants (from reference)
#define NB 4
#define NN 20000
#define NE 320000
#define HH 128

#define EBLK 64      // deg histogram blocks
#define HTHR 1024
#define RB 79        // reduce_deg blocks (ceil(NN/256))

#define FBLK 256     // fused kernel: exactly 256 blocks (1/CU worst case)
#define FTHR 1024
#define SEDG (NE / FBLK)   // 1250 edges per block in the s phase
#define WBLK 250     // wsum worker blocks (250 x 80 nodes = 20000 exactly)
#define PER 80
#define NSEC 8

// ws float layout:
//   pdeg [EBLK][NN]    per-block degree partials (plain, boundary-protected)
//   dinv [NN]          rsqrt(deg+1)              (plain, boundary-protected)
//   s    [NN]          sum_{e:src=n} dinv[dst]   (atomic RMW inside fused k.)
//   v    [NSEC][NB*HH] pooled sums (sectored atomic RMW)
//   cnts [18] ints     subS[8], masS, subW[8], masW
#define OFF_PDEG 0
#define OFF_DINV (EBLK * NN)
#define OFF_S    (OFF_DINV + NN)
#define OFF_V    (OFF_S + NN)
#define OFF_CNT  (OFF_V + NSEC * NB * HH)

// --- K1: per-block LDS degree histogram; block 0 also pre-zeroes s, v, cnts
//     (all consumed >=1 kernel boundary later -> plain stores are safe). ---
__global__ void __launch_bounds__(HTHR) deg_hist_kernel(
        const int* __restrict__ dst, float* __restrict__ pdeg,
        float* __restrict__ s, float* __restrict__ v, int* __restrict__ cnts) {
    __shared__ float hist[NN];   // 80 KB
    const int t = threadIdx.x, bk = blockIdx.x;
    if (bk == 0) {
        for (int i = t; i < NN; i += HTHR) s[i] = 0.0f;
        for (int i = t; i < NSEC * NB * HH; i += HTHR) v[i] = 0.0f;
        if (t < 18) cnts[t] = 0;
    }
    for (int i = t; i < NN; i += HTHR) hist[i] = 0.0f;
    __syncthreads();
    for (int e = bk * HTHR + t; e < NE; e += EBLK * HTHR)
        atomicAdd(&hist[dst[e]], 1.0f);          // LDS atomic
    __syncthreads();
    float* out = pdeg + (size_t)bk * NN;
    for (int i = t; i < NN; i += HTHR) out[i] = hist[i];  // coalesced dump
}

// --- K2: dinv[n] = rsqrt(1 + sum_c pdeg[c][n]) (pure, boundary-protected) ---
__global__ void reduce_deg_kernel(const float* __restrict__ pdeg,
                                  float* __restrict__ dinv) {
    const int n = blockIdx.x * 256 + threadIdx.x;
    if (n >= NN) return;
    float acc = 1.0f;  // self-loop
    #pragma unroll 8
    for (int c = 0; c < EBLK; ++c) acc += pdeg[(size_t)c * NN + n];
    dinv[n] = rsqrtf(acc);
}

#define FMA4(D, W, X) { D.x += (W)*(X).x; D.y += (W)*(X).y; \
                        D.z += (W)*(X).z; D.w += (W)*(X).w; }

// --- K3: phase-sequential fused kernel (256 blocks x 1024 threads).
// Phase S (all blocks): LDS s-histogram over a 1250-edge slice, nonzero bins
//   atomicAdd'ed into global s (coherent-point RMW; R14-proven protocol).
// Phase W (blocks 0..249): w[n] inline from s (RMW reads) + dinv, weighted
//   feature sum over 80 nodes x 4 batches, sectored v atomics.
// Phase M (block 255): warms Wg/W1 overlapping phase W, spins on masW,
//   runs the 2-layer MLP head from one block.
// All cross-block data inside this kernel flows through atomic RMWs only;
// each signal is preceded by a vmcnt drain (__syncthreads or explicit).
__global__ void __launch_bounds__(FTHR) fused_kernel(
    const float* __restrict__ fa, const float* __restrict__ fb,
    const int* __restrict__ src, const int* __restrict__ dst,
    const float* __restrict__ dinv, float* __restrict__ s,
    const float* __restrict__ Wg, const float* __restrict__ bg,
    const float* __restrict__ W1, const float* __restrict__ b1,
    const float* __restrict__ W2, const float* __restrict__ b2,
    float* __restrict__ v, int* __restrict__ cnts, float* __restrict__ out)
{
    __shared__ __align__(16) float sh[NN];   // 80 KB, role-dependent reuse
    int* subS = cnts;
    int* masS = cnts + 8;
    int* subW = cnts + 9;
    int* masW = cnts + 17;
    const int t = threadIdx.x, bk = blockIdx.x;

    // ---- Phase S: s-histogram (all 256 blocks) ----
    for (int i = t; i < NN; i += FTHR) sh[i] = 0.0f;
    __syncthreads();
    {
        const int e0 = bk * SEDG;
        for (int e = e0 + t; e < e0 + SEDG; e += FTHR)
            atomicAdd(&sh[src[e]], dinv[dst[e]]);   // LDS atomic
    }
    __syncthreads();
    for (int i = t; i < NN; i += FTHR) {
        const float hv = sh[i];
        if (hv != 0.0f) atomicAdd(&s[i], hv);       // coherent-point RMW
    }
    __syncthreads();   // every wave drains its own vmem ops before barrier
    if (t == 0) {
        int old = atomicAdd(&subS[bk & 7], 1);
        if (old == FBLK / NSEC - 1) atomicAdd(masS, 1);
    }

    // ---- Phase W: weighted feature sum (blocks 0..WBLK-1) ----
    if (bk < WBLK) {
        if (t == 0) {
            while (atomicAdd(masS, 0) < NSEC) __builtin_amdgcn_s_sleep(16);
        }
        __syncthreads();

        const int n0 = bk * PER;
        if (t < PER) {
            const int n = n0 + t;
            const float sv = atomicAdd(&s[n], 0.0f);   // coherent RMW read
            const float di = dinv[n];
            sh[t] = di * (di + sv);                    // w[n]
        }
        __syncthreads();

        const int g = t >> 5, q = t & 31;   // 32 node-groups x 32 feat-lanes
        const float wA = sh[g], wB = sh[g + 32];
        const bool three = (t < 512);       // g<16: third node (wave-uniform)
        const float wC = three ? sh[g + 64] : 0.0f;
        __syncthreads();                    // w in regs before sh is reused

        const float* base = (q < 16) ? (fa + (size_t)q * 4)
                                     : (fb + (size_t)(q - 16) * 4);
        const int nA = n0 + g, nB = n0 + g + 32, nC = n0 + g + 64;
        #define LD(B, N) (*reinterpret_cast<const float4*>( \
                              base + ((size_t)(B) * NN + (N)) * 64))
        // 8 independent loads issued before any FMA
        float4 xA0 = LD(0, nA), xA1 = LD(1, nA), xA2 = LD(2, nA), xA3 = LD(3, nA);
        float4 xB0 = LD(0, nB), xB1 = LD(1, nB), xB2 = LD(2, nB), xB3 = LD(3, nB);
        float4 ac0 = make_float4(0.f, 0.f, 0.f, 0.f);
        float4 ac1 = ac0, ac2 = ac0, ac3 = ac0;
        FMA4(ac0, wA, xA0) FMA4(ac1, wA, xA1) FMA4(ac2, wA, xA2) FMA4(ac3, wA, xA3)
        FMA4(ac0, wB, xB0) FMA4(ac1, wB, xB1) FMA4(ac2, wB, xB2) FMA4(ac3, wB, xB3)
        if (three) {
            float4 xC0 = LD(0, nC), xC1 = LD(1, nC), xC2 = LD(2, nC), xC3 = LD(3, nC);
            FMA4(ac0, wC, xC0) FMA4(ac1, wC, xC1) FMA4(ac2, wC, xC2) FMA4(ac3, wC, xC3)
        }

        float4* sm = reinterpret_cast<float4*>(sh);
        float* vsec = v + (size_t)(bk & (NSEC - 1)) * (NB * HH);
        #define PHASE(AC, B) { \
            sm[t] = AC; __syncthreads(); \
            if (t < 32) { \
                float4 r = sm[t]; \
                _Pragma("unroll") \
                for (int gg = 1; gg < 32; ++gg) { \
                    float4 o = sm[gg * 32 + t]; \
                    r.x += o.x; r.y += o.y; r.z += o.z; r.w += o.w; } \
                const int k = (t < 16) ? t * 4 : 64 + (t - 16) * 4; \
                float* vb = vsec + (B) * HH + k; \
                atomicAdd(vb + 0, r.x); atomicAdd(vb + 1, r.y); \
                atomicAdd(vb + 2, r.z); atomicAdd(vb + 3, r.w); } \
            __syncthreads(); }
        PHASE(ac0, 0) PHASE(ac1, 1) PHASE(ac2, 2) PHASE(ac3, 3)
    }

    // every block signals W completion (idle blocks immediately)
    if (t == 0) {
        // t0 is in wave 0, which issued ALL of this block's v-atomics.
        asm volatile("s_waitcnt vmcnt(0)" ::: "memory");
        int old = atomicAdd(&subW[bk & 7], 1);
        if (old == FBLK / NSEC - 1) atomicAdd(masW, 1);
    }

    // ---- Phase M: block FBLK-1 runs the MLP head ----
    if (bk == FBLK - 1) {
        // warm Wg/W1 into cache while workers finish (kept live, no DCE)
        float warm = 0.0f;
        for (int i = t; i < HH * HH / 4; i += FTHR) {
            float4 a = ((const float4*)Wg)[i];
            float4 b = ((const float4*)W1)[i];
            warm += a.x + a.w + b.x + b.w;
        }
        asm volatile("" :: "v"(warm));
        if (t == 0) {
            while (atomicAdd(masW, 0) < NSEC) __builtin_amdgcn_s_sleep(16);
        }
        __syncthreads();

        float* xs  = sh;             // 512 floats
        float* ys  = sh + 512;       // 512 floats
        float* red = sh + 1024;      // 512 floats
        const int half = t >> 9;         // 0/1: j-range split
        const int idx  = t & 511;
        const int bb = idx >> 7, kk = idx & 127;

        if (t < 512) {
            float val = 0.0f;
            #pragma unroll
            for (int sct = 0; sct < NSEC; ++sct)
                val += atomicAdd(&v[sct * (NB * HH) + t], 0.0f);  // RMW reads
            xs[t] = val * (1.0f / NN);
        }
        __syncthreads();

        // layer 1: pooled = xs @ Wg + bg  (j split across the two halves)
        float p1 = (half == 0) ? bg[kk] : 0.0f;
        #pragma unroll 8
        for (int j = half * 64; j < half * 64 + 64; ++j)
            p1 += xs[bb * HH + j] * Wg[j * HH + kk];
        if (half == 1) red[idx] = p1;
        __syncthreads();
        if (half == 0) ys[idx] = p1 + red[idx];
        __syncthreads();

        // layer 2: hid = relu(ys @ W1 + b1), folded W2 scale
        float p2 = (half == 0) ? b1[kk] : 0.0f;
        #pragma unroll 8
        for (int j = half * 64; j < half * 64 + 64; ++j)
            p2 += ys[bb * HH + j] * W1[j * HH + kk];
        if (half == 1) red[idx] = p2;
        __syncthreads();
        if (half == 0) {
            float h = fmaxf(p2 + red[idx], 0.0f);
            red[idx] = h * W2[kk];
        }
        __syncthreads();

        // tree-reduce 128 -> 1 per batch
        for (int off = 64; off > 0; off >>= 1) {
            if (t < 512 && kk < off) red[bb * HH + kk] += red[bb * HH + kk + off];
            __syncthreads();
        }
        if (t < 512 && kk == 0) out[bb] = red[bb * HH] + b2[0];
    }
}

extern "C" void kernel_launch(void* const* d_in, const int* in_sizes, int n_in,
                              void* d_out, int out_size, void* d_ws, size_t ws_size,
                              hipStream_t stream) {
    const float* fa = (const float*)d_in[0];   // [B,N,64]
    const float* fb = (const float*)d_in[1];   // [B,N,64]
    const int*   ei = (const int*)d_in[2];     // [2,E]
    const float* Wg = (const float*)d_in[3];   // [H,H]
    const float* bg = (const float*)d_in[4];   // [H]
    const float* W1 = (const float*)d_in[5];   // [H,H]
    const float* b1 = (const float*)d_in[6];   // [H]
    const float* W2 = (const float*)d_in[7];   // [H,1]
    const float* b2 = (const float*)d_in[8];   // [1]
    float* out = (float*)d_out;

    const int* src = ei;
    const int* dst = ei + NE;

    float* ws   = (float*)d_ws;
    float* pdeg = ws + OFF_PDEG;
    float* dinv = ws + OFF_DINV;
    float* s    = ws + OFF_S;
    float* v    = ws + OFF_V;
    int*   cnts = (int*)(ws + OFF_CNT);

    deg_hist_kernel<<<EBLK, HTHR, 0, stream>>>(dst, pdeg, s, v, cnts);

    reduce_deg_kernel<<<RB, 256, 0, stream>>>(pdeg, dinv);

    void* args[] = {
        (void*)&fa, (void*)&fb, (void*)&src, (void*)&dst,
        (void*)&dinv, (void*)&s,
        (void*)&Wg, (void*)&bg, (void*)&W1, (void*)&b1,
        (void*)&W2, (void*)&b2,
        (void*)&v, (void*)&cnts, (void*)&out
    };
    hipError_t cerr = hipLaunchCooperativeKernel((void*)fused_kernel,
                                                 dim3(FBLK), dim3(FTHR),
                                                 args, 0, stream);
    if (cerr != hipSuccess) {
        // capacity fallback: 256 blocks x 80KB LDS is <= 1 block/CU x 256 CUs,
        // so a plain launch is also fully co-resident (deterministic path).
        fused_kernel<<<dim3(FBLK), dim3(FTHR), 0, stream>>>(
            fa, fb, src, dst, dinv, s, Wg, bg, W1, b1, W2, b2, v, cnts, out);
    }
}

// Round 17
// 56.894 us; speedup vs baseline: 1.4919x; 1.4919x over previous
//
#include <hip/hip_runtime.h>

// Problem constants (from reference)
#define NB 4
#define NN 20000
#define NE 320000
#define HH 128

#define EBLK 64     // histogram blocks (each holds a full 80 KB LDS histogram)
#define HTHR 1024   // threads per histogram block
#define CHUNKS 512  // node chunks for the weighted-sum kernel (2 blocks/CU)
#define WTHR 512    // threads per wsum block
#define PER 40      // nodes per chunk (512 x 40 = 20480 >= 20000)
#define NSEC 16     // v sectors: 512 workers / 16 = 32 adds per address

#define RB 79       // reduce_deg blocks ( ceil(NN/256) )

// ws layout (floats):
//   pdeg   [EBLK][NN]     per-block degree partials
//   dinv   [NN]           rsqrt(deg+1)
//   ps     [EBLK][NN]     per-block s partials
//   v      [NSEC][NB*HH]  pooled feature sums (sectored atomic accum)
//   cnts   [17] ints      sub[16] sector counters + master
#define OFF_PDEG 0
#define OFF_DINV (EBLK * NN)
#define OFF_PS   (OFF_DINV + NN)
#define OFF_V    (OFF_PS + EBLK * NN)
#define OFF_CNT  (OFF_V + NSEC * NB * HH)

// --- K1: per-block LDS degree histogram (NO global atomics) ---
__global__ void __launch_bounds__(HTHR) deg_hist_kernel(
        const int* __restrict__ dst, float* __restrict__ pdeg) {
    __shared__ __align__(16) float hist[NN];   // 80 KB
    const int t = threadIdx.x, bk = blockIdx.x;
    float4* h4 = (float4*)hist;
    const float4 z4 = make_float4(0.f, 0.f, 0.f, 0.f);
    for (int i = t; i < NN / 4; i += HTHR) h4[i] = z4;
    __syncthreads();
    for (int e = bk * HTHR + t; e < NE; e += EBLK * HTHR)
        atomicAdd(&hist[dst[e]], 1.0f);          // LDS atomic (ds_add_f32)
    __syncthreads();
    float4* out = (float4*)(pdeg + (size_t)bk * NN);
    for (int i = t; i < NN / 4; i += HTHR) out[i] = h4[i];  // dwordx4 dump
}

// --- K2: dinv[n] = rsqrt(1 + sum_c pdeg[c][n]); block 0 zeroes v + counters.
//         (Plain stores are safe: the kernel boundary flushes L2 before K4.) ---
__global__ void reduce_deg_kernel(const float* __restrict__ pdeg,
                                  float* __restrict__ dinv,
                                  float* __restrict__ v, int* __restrict__ cnts) {
    if (blockIdx.x == 0) {
        #pragma unroll
        for (int u = 0; u < NSEC * NB * HH / 256; ++u)
            v[u * 256 + threadIdx.x] = 0.0f;
        if (threadIdx.x < 17) cnts[threadIdx.x] = 0;   // sub[16] + master
    }
    const int n = blockIdx.x * 256 + threadIdx.x;
    if (n >= NN) return;
    float acc = 1.0f;  // self-loop
    #pragma unroll 8
    for (int c = 0; c < EBLK; ++c) acc += pdeg[(size_t)c * NN + n];
    dinv[n] = rsqrtf(acc);
}

// --- K3: per-block LDS s histogram: s[src] += dinv[dst] ---
__global__ void __launch_bounds__(HTHR) s_hist_kernel(
        const int* __restrict__ src, const int* __restrict__ dst,
        const float* __restrict__ dinv, float* __restrict__ ps) {
    __shared__ __align__(16) float hist[NN];   // 80 KB
    const int t = threadIdx.x, bk = blockIdx.x;
    float4* h4 = (float4*)hist;
    const float4 z4 = make_float4(0.f, 0.f, 0.f, 0.f);
    for (int i = t; i < NN / 4; i += HTHR) h4[i] = z4;
    __syncthreads();
    for (int e = bk * HTHR + t; e < NE; e += EBLK * HTHR)
        atomicAdd(&hist[src[e]], dinv[dst[e]]);  // L2 gather + LDS atomic
    __syncthreads();
    float4* out = (float4*)(ps + (size_t)bk * NN);
    for (int i = t; i < NN / 4; i += HTHR) out[i] = h4[i];
}

// --- K4: weighted feature sum (workers, blocks 1..512) + MLP block (block 0).
// Small LDS (~16 KB) -> 2 blocks/CU, 16 waves/CU: wave-level parallelism
// hides the feature-load latency (R10 showed per-wave ILP alone does not).
// v sectored by (chunk&15): per-address atomic chain stays at 32 (R13 win).
// Completion: hierarchical sub[16]+master counters; MLP block warms Wg/W1
// into its cache while spinning, then runs the head from cache.
__global__ void __launch_bounds__(WTHR) wsum_mlp_kernel(
        const float* __restrict__ fa, const float* __restrict__ fb,
        const float* __restrict__ dinv, const float* __restrict__ ps,
        const float* __restrict__ Wg, const float* __restrict__ bg,
        const float* __restrict__ W1, const float* __restrict__ b1,
        const float* __restrict__ W2, const float* __restrict__ b2,
        float* __restrict__ v, int* __restrict__ cnts,
        float* __restrict__ out) {
    __shared__ float xs[NB * HH];
    __shared__ float ys[NB * HH];
    __shared__ float red[NB * HH];
    __shared__ float wl[PER];
    __shared__ float wpart[PER][8];
    __shared__ float4 smem[WTHR];
    int* sub = cnts;
    int* master = cnts + 16;
    const int t = threadIdx.x;

    if (blockIdx.x == 0) {
        // ---- MLP block: warm Wg/W1 into cache, spin, compute head ----
        float warm = 0.0f;
        for (int i = t; i < HH * HH / 4; i += WTHR) {
            float4 a = ((const float4*)Wg)[i];
            float4 b = ((const float4*)W1)[i];
            warm += a.x + a.w + b.x + b.w;
        }
        asm volatile("" :: "v"(warm));   // keep warm loads alive (no DCE)
        if (t == 0) {
            while (atomicAdd(master, 0) < NSEC) __builtin_amdgcn_s_sleep(16);
        }
        __syncthreads();

        // sector-reduce v (16 independent coherent RMW reads per thread)
        float val = 0.0f;
        #pragma unroll
        for (int s = 0; s < NSEC; ++s)
            val += atomicAdd(&v[s * (NB * HH) + t], 0.0f);
        xs[t] = val * (1.0f / NN);
        __syncthreads();

        const int bb = t >> 7;           // 0..3
        const int kk = t & (HH - 1);     // 0..127

        // layer 1: pooled = xs @ Wg + bg   (Wg is cache-warm)
        float a1 = bg[kk];
        #pragma unroll 8
        for (int j = 0; j < HH; ++j) a1 += xs[bb * HH + j] * Wg[j * HH + kk];
        ys[t] = a1;
        __syncthreads();

        // layer 2: hid = relu(ys @ W1 + b1), fold W2 scale
        float a2 = b1[kk];
        #pragma unroll 8
        for (int j = 0; j < HH; ++j) a2 += ys[bb * HH + j] * W1[j * HH + kk];
        a2 = fmaxf(a2, 0.0f);
        red[t] = a2 * W2[kk];
        __syncthreads();

        // tree-reduce 128 -> 1 per batch
        #pragma unroll
        for (int off = HH / 2; off > 0; off >>= 1) {
            if (kk < off) red[bb * HH + kk] += red[bb * HH + kk + off];
            __syncthreads();
        }
        if (kk == 0) out[bb] = red[bb * HH] + b2[0];
        return;
    }

    // ---- worker blocks: chunk c = blockIdx.x - 1 (0..511) ----
    const int c = blockIdx.x - 1;
    const int n0 = c * PER;
    const int n1 = min(NN, n0 + PER);
    const int cnt = n1 - n0;             // <= 0 for c >= 500
    float* vsec = v + (size_t)(c & (NSEC - 1)) * (NB * HH);

    if (cnt > 0) {
        // prologue: wpart[i][s] = sum of 8 ps rows (slice s) at node n0+i
        for (int idx = t; idx < cnt * 8; idx += WTHR) {
            const int i = idx >> 3, s = idx & 7;
            const int n = n0 + i;
            float a = 0.0f;
            #pragma unroll
            for (int u = 0; u < 8; ++u) a += ps[(size_t)(s * 8 + u) * NN + n];
            wpart[i][s] = a;
        }
        __syncthreads();
        for (int i = t; i < cnt; i += WTHR) {
            float a = 0.0f;
            #pragma unroll
            for (int s = 0; s < 8; ++s) a += wpart[i][s];
            const float di = dinv[n0 + i];
            wl[i] = di * (di + a);
        }
        __syncthreads();

        const int g = t >> 5;        // node subgroup 0..15
        const int q = t & 31;
        const float* base = (q < 16) ? (fa + (size_t)q * 4)
                                     : (fb + (size_t)(q - 16) * 4);

        float4 acc[NB];
        #pragma unroll
        for (int b = 0; b < NB; ++b) acc[b] = make_float4(0.f, 0.f, 0.f, 0.f);

        for (int n = n0 + g; n < n1; n += 16) {
            const float wn = wl[n - n0];
            #pragma unroll
            for (int b = 0; b < NB; ++b) {
                float4 x = *reinterpret_cast<const float4*>(
                    base + ((size_t)b * NN + n) * 64);
                acc[b].x += wn * x.x; acc[b].y += wn * x.y;
                acc[b].z += wn * x.z; acc[b].w += wn * x.w;
            }
        }

        #pragma unroll
        for (int b = 0; b < NB; ++b) {
            smem[t] = acc[b];
            __syncthreads();
            if (t < 32) {    // wave 0 issues ALL of this block's v-atomics
                float4 r = smem[t];
                #pragma unroll
                for (int gg = 1; gg < 16; ++gg) {
                    float4 o = smem[gg * 32 + t];
                    r.x += o.x; r.y += o.y; r.z += o.z; r.w += o.w;
                }
                const int k = (t < 16) ? t * 4 : 64 + (t - 16) * 4;
                float* vb = vsec + b * HH + k;
                atomicAdd(vb + 0, r.x);
                atomicAdd(vb + 1, r.y);
                atomicAdd(vb + 2, r.z);
                atomicAdd(vb + 3, r.w);
            }
            __syncthreads();
        }
    }

    if (t == 0) {
        // wave 0 waits for its own v-atomics to reach the coherent point,
        // then signals via the hierarchical counter. No fences anywhere.
        asm volatile("s_waitcnt vmcnt(0)" ::: "memory");
        int old = atomicAdd(&sub[c & (NSEC - 1)], 1);
        if (old == (CHUNKS / NSEC) - 1) atomicAdd(master, 1);
    }
}

extern "C" void kernel_launch(void* const* d_in, const int* in_sizes, int n_in,
                              void* d_out, int out_size, void* d_ws, size_t ws_size,
                              hipStream_t stream) {
    const float* fa = (const float*)d_in[0];   // [B,N,64]
    const float* fb = (const float*)d_in[1];   // [B,N,64]
    const int*   ei = (const int*)d_in[2];     // [2,E]
    const float* Wg = (const float*)d_in[3];   // [H,H]
    const float* bg = (const float*)d_in[4];   // [H]
    const float* W1 = (const float*)d_in[5];   // [H,H]
    const float* b1 = (const float*)d_in[6];   // [H]
    const float* W2 = (const float*)d_in[7];   // [H,1]
    const float* b2 = (const float*)d_in[8];   // [1]
    float* out = (float*)d_out;

    const int* src = ei;
    const int* dst = ei + NE;

    float* ws   = (float*)d_ws;
    float* pdeg = ws + OFF_PDEG;
    float* dinv = ws + OFF_DINV;
    float* ps   = ws + OFF_PS;
    float* v    = ws + OFF_V;
    int*   cnts = (int*)(ws + OFF_CNT);

    deg_hist_kernel<<<EBLK, HTHR, 0, stream>>>(dst, pdeg);

    reduce_deg_kernel<<<RB, 256, 0, stream>>>(pdeg, dinv, v, cnts);

    s_hist_kernel<<<EBLK, HTHR, 0, stream>>>(src, dst, dinv, ps);

    wsum_mlp_kernel<<<CHUNKS + 1, WTHR, 0, stream>>>(fa, fb, dinv, ps,
                                                     Wg, bg, W1, b1, W2, b2,
                                                     v, cnts, out);
}

// Round 18
// 50.510 us; speedup vs baseline: 1.6804x; 1.1264x over previous
//
#include <hip/hip_runtime.h>

// Problem constants (from reference)
#define NB 4
#define NN 20000
#define NE 320000
#define HH 128

#define EBLK 64     // histogram blocks (each holds a full 80 KB LDS histogram)
#define HTHR 1024   // threads per histogram block
#define CHUNKS 256  // node chunks for the weighted-sum kernel
#define WTHR 512    // threads per wsum block (16 node-groups x 32 lanes)
#define PER 79      // ceil(NN/CHUNKS) nodes per chunk
#define NSEC 8      // v sectors (cuts per-address atomic contention)

#define RB 79       // reduce_deg blocks ( ceil(NN/256) )

// ws layout (floats):
//   pdeg   [EBLK][NN]     per-block degree partials
//   dinv   [NN]           rsqrt(deg+1)
//   ps     [EBLK][NN]     per-block s partials
//   v      [NSEC][NB*HH]  pooled feature sums (sectored atomic accum)
//   cnts   [9] ints       sub[8] sector counters + master
#define OFF_PDEG 0
#define OFF_DINV (EBLK * NN)
#define OFF_PS   (OFF_DINV + NN)
#define OFF_V    (OFF_PS + EBLK * NN)
#define OFF_CNT  (OFF_V + NSEC * NB * HH)

// --- K1: per-block LDS degree histogram (NO global atomics) ---
__global__ void __launch_bounds__(HTHR) deg_hist_kernel(
        const int* __restrict__ dst, float* __restrict__ pdeg) {
    __shared__ __align__(16) float hist[NN];   // 80 KB
    const int t = threadIdx.x, bk = blockIdx.x;
    float4* h4 = (float4*)hist;
    const float4 z4 = make_float4(0.f, 0.f, 0.f, 0.f);
    for (int i = t; i < NN / 4; i += HTHR) h4[i] = z4;
    __syncthreads();
    for (int e = bk * HTHR + t; e < NE; e += EBLK * HTHR)
        atomicAdd(&hist[dst[e]], 1.0f);          // LDS atomic (ds_add_f32)
    __syncthreads();
    float4* out = (float4*)(pdeg + (size_t)bk * NN);
    for (int i = t; i < NN / 4; i += HTHR) out[i] = h4[i];  // dwordx4 dump
}

// --- K2: dinv[n] = rsqrt(1 + sum_c pdeg[c][n]); block 0 zeroes v + counters.
//         (Plain stores are safe: the kernel boundary flushes L2 before K4.) ---
__global__ void reduce_deg_kernel(const float* __restrict__ pdeg,
                                  float* __restrict__ dinv,
                                  float* __restrict__ v, int* __restrict__ cnts) {
    if (blockIdx.x == 0) {
        #pragma unroll
        for (int u = 0; u < NSEC * NB * HH / 256; ++u)
            v[u * 256 + threadIdx.x] = 0.0f;
        if (threadIdx.x < 9) cnts[threadIdx.x] = 0;   // sub[8] + master
    }
    const int n = blockIdx.x * 256 + threadIdx.x;
    if (n >= NN) return;
    float acc = 1.0f;  // self-loop
    #pragma unroll 8
    for (int c = 0; c < EBLK; ++c) acc += pdeg[(size_t)c * NN + n];
    dinv[n] = rsqrtf(acc);
}

// --- K3: per-block LDS s histogram: s[src] += dinv[dst] ---
__global__ void __launch_bounds__(HTHR) s_hist_kernel(
        const int* __restrict__ src, const int* __restrict__ dst,
        const float* __restrict__ dinv, float* __restrict__ ps) {
    __shared__ __align__(16) float hist[NN];   // 80 KB
    const int t = threadIdx.x, bk = blockIdx.x;
    float4* h4 = (float4*)hist;
    const float4 z4 = make_float4(0.f, 0.f, 0.f, 0.f);
    for (int i = t; i < NN / 4; i += HTHR) h4[i] = z4;
    __syncthreads();
    for (int e = bk * HTHR + t; e < NE; e += EBLK * HTHR)
        atomicAdd(&hist[src[e]], dinv[dst[e]]);  // L2 gather + LDS atomic
    __syncthreads();
    float4* out = (float4*)(ps + (size_t)bk * NN);
    for (int i = t; i < NN / 4; i += HTHR) out[i] = h4[i];
}

// --- K4: weighted feature sum (workers, blocks 1..256) + MLP block (block 0).
// Workers: 16 node-groups x 32 lanes, 4-deep node unroll x 4 batches = 16
// independent float4 loads in flight; v sectored by (chunk&7).
// Completion: hierarchical counters -- sub[c&7] (32 blocks each), 32nd
// incrementer bumps master. Max same-address chain: 32 instead of 256.
// Block 0: prefetches Wg into LDS (warms W1 to L3) while workers run, spins
// on master with s_sleep, then runs both GEMV layers from LDS.
__global__ void __launch_bounds__(WTHR) wsum_mlp_kernel(
        const float* __restrict__ fa, const float* __restrict__ fb,
        const float* __restrict__ dinv, const float* __restrict__ ps,
        const float* __restrict__ Wg, const float* __restrict__ bg,
        const float* __restrict__ W1, const float* __restrict__ b1,
        const float* __restrict__ W2, const float* __restrict__ b2,
        float* __restrict__ v, int* __restrict__ cnts,
        float* __restrict__ out) {
    __shared__ float WL[HH * HH];        // 64 KB weight tile (block 0 only)
    __shared__ float xs[NB * HH];
    __shared__ float ys[NB * HH];
    __shared__ float red[NB * HH];
    __shared__ float wl[PER];
    __shared__ float wpart[PER][8];
    __shared__ float4 smem[WTHR];
    int* sub = cnts;
    int* master = cnts + 8;
    const int t = threadIdx.x;

    if (blockIdx.x == 0) {
        // ---- MLP block: prefetch Wg -> LDS, warm W1 -> L3, spin, compute ----
        const float4* wgv = (const float4*)Wg;
        const float4* w1v = (const float4*)W1;
        float4* wlv = (float4*)WL;
        float warm = 0.0f;
        for (int i = t; i < HH * HH / 4; i += WTHR) {
            wlv[i] = wgv[i];                 // Wg -> LDS
            float4 y = w1v[i];               // W1 -> L3 (kept live, no DCE)
            warm += y.x + y.w;
        }
        asm volatile("" :: "v"(warm));
        if (t == 0) {
            while (atomicAdd(master, 0) < NSEC) __builtin_amdgcn_s_sleep(8);
        }
        __syncthreads();

        // sector-reduce v (8 independent coherent RMW reads in flight)
        float val = 0.0f;
        #pragma unroll
        for (int s = 0; s < NSEC; ++s)
            val += atomicAdd(&v[s * (NB * HH) + t], 0.0f);
        xs[t] = val * (1.0f / NN);
        __syncthreads();

        const int bb = t >> 7;           // 0..3
        const int kk = t & (HH - 1);     // 0..127

        // layer 1 from LDS: pooled = xs @ Wg + bg
        float a1 = bg[kk];
        #pragma unroll 8
        for (int j = 0; j < HH; ++j) a1 += xs[bb * HH + j] * WL[j * HH + kk];
        ys[t] = a1;
        __syncthreads();

        // swap in W1 (L3-warm) and run layer 2
        for (int i = t; i < HH * HH / 4; i += WTHR) wlv[i] = w1v[i];
        __syncthreads();
        float a2 = b1[kk];
        #pragma unroll 8
        for (int j = 0; j < HH; ++j) a2 += ys[bb * HH + j] * WL[j * HH + kk];
        a2 = fmaxf(a2, 0.0f);
        red[t] = a2 * W2[kk];
        __syncthreads();

        // tree-reduce 128 -> 1 per batch
        #pragma unroll
        for (int off = HH / 2; off > 0; off >>= 1) {
            if (kk < off) red[bb * HH + kk] += red[bb * HH + kk + off];
            __syncthreads();
        }
        if (kk == 0) out[bb] = red[bb * HH] + b2[0];
        return;
    }

    // ---- worker blocks: chunk c = blockIdx.x - 1 ----
    const int c = blockIdx.x - 1;
    const int n0 = c * PER;
    const int n1 = min(NN, n0 + PER);
    const int cnt = n1 - n0;             // may be <= 0 for the last blocks
    float* vsec = v + (size_t)(c & (NSEC - 1)) * (NB * HH);

    if (cnt > 0) {
        // prologue: wpart[i][s] = sum of 8 ps rows (slice s) at node n0+i
        for (int idx = t; idx < cnt * 8; idx += WTHR) {
            const int i = idx >> 3, s = idx & 7;
            const int n = n0 + i;
            float a = 0.0f;
            #pragma unroll
            for (int u = 0; u < 8; ++u) a += ps[(size_t)(s * 8 + u) * NN + n];
            wpart[i][s] = a;
        }
        __syncthreads();
        for (int i = t; i < cnt; i += WTHR) {
            float a = 0.0f;
            #pragma unroll
            for (int s = 0; s < 8; ++s) a += wpart[i][s];
            const float di = dinv[n0 + i];
            wl[i] = di * (di + a);
        }
        __syncthreads();

        const int g = t >> 5;        // node subgroup 0..15
        const int q = t & 31;
        const float* base = (q < 16) ? (fa + (size_t)q * 4)
                                     : (fb + (size_t)(q - 16) * 4);

        float4 acc[NB];
        #pragma unroll
        for (int b = 0; b < NB; ++b) acc[b] = make_float4(0.f, 0.f, 0.f, 0.f);

        int n = n0 + g;
        // main: 4 nodes x 4 batches = 16 independent float4 loads in flight
        for (; n + 48 < n1; n += 64) {
            const float w0 = wl[n - n0];
            const float w1 = wl[n + 16 - n0];
            const float w2 = wl[n + 32 - n0];
            const float w3 = wl[n + 48 - n0];
            #pragma unroll
            for (int b = 0; b < NB; ++b) {
                const float* p = base + ((size_t)b * NN + n) * 64;
                float4 x0 = *reinterpret_cast<const float4*>(p);
                float4 x1 = *reinterpret_cast<const float4*>(p + 16 * 64);
                float4 x2 = *reinterpret_cast<const float4*>(p + 32 * 64);
                float4 x3 = *reinterpret_cast<const float4*>(p + 48 * 64);
                acc[b].x += w0 * x0.x + w1 * x1.x + w2 * x2.x + w3 * x3.x;
                acc[b].y += w0 * x0.y + w1 * x1.y + w2 * x2.y + w3 * x3.y;
                acc[b].z += w0 * x0.z + w1 * x1.z + w2 * x2.z + w3 * x3.z;
                acc[b].w += w0 * x0.w + w1 * x1.w + w2 * x2.w + w3 * x3.w;
            }
        }
        for (; n < n1; n += 16) {     // remainder (<= 3 nodes per g)
            const float wn = wl[n - n0];
            #pragma unroll
            for (int b = 0; b < NB; ++b) {
                float4 x = *reinterpret_cast<const float4*>(
                    base + ((size_t)b * NN + n) * 64);
                acc[b].x += wn * x.x; acc[b].y += wn * x.y;
                acc[b].z += wn * x.z; acc[b].w += wn * x.w;
            }
        }

        #pragma unroll
        for (int b = 0; b < NB; ++b) {
            smem[t] = acc[b];
            __syncthreads();
            if (t < 32) {    // wave 0 issues ALL of this block's v-atomics
                float4 r = smem[t];
                #pragma unroll
                for (int gg = 1; gg < 16; ++gg) {
                    float4 o = smem[gg * 32 + t];
                    r.x += o.x; r.y += o.y; r.z += o.z; r.w += o.w;
                }
                const int k = (t < 16) ? t * 4 : 64 + (t - 16) * 4;
                float* vb = vsec + b * HH + k;
                atomicAdd(vb + 0, r.x);
                atomicAdd(vb + 1, r.y);
                atomicAdd(vb + 2, r.z);
                atomicAdd(vb + 3, r.w);
            }
            __syncthreads();
        }
    }

    if (t == 0) {
        // wave 0 waits for its own v-atomics to reach the coherent point,
        // then signals via the hierarchical counter. No fences anywhere.
        asm volatile("s_waitcnt vmcnt(0)" ::: "memory");
        int old = atomicAdd(&sub[c & (NSEC - 1)], 1);
        if (old == (CHUNKS / NSEC) - 1) atomicAdd(master, 1);
    }
}

extern "C" void kernel_launch(void* const* d_in, const int* in_sizes, int n_in,
                              void* d_out, int out_size, void* d_ws, size_t ws_size,
                              hipStream_t stream) {
    const float* fa = (const float*)d_in[0];   // [B,N,64]
    const float* fb = (const float*)d_in[1];   // [B,N,64]
    const int*   ei = (const int*)d_in[2];     // [2,E]
    const float* Wg = (const float*)d_in[3];   // [H,H]
    const float* bg = (const float*)d_in[4];   // [H]
    const float* W1 = (const float*)d_in[5];   // [H,H]
    const float* b1 = (const float*)d_in[6];   // [H]
    const float* W2 = (const float*)d_in[7];   // [H,1]
    const float* b2 = (const float*)d_in[8];   // [1]
    float* out = (float*)d_out;

    const int* src = ei;
    const int* dst = ei + NE;

    float* ws   = (float*)d_ws;
    float* pdeg = ws + OFF_PDEG;
    float* dinv = ws + OFF_DINV;
    float* ps   = ws + OFF_PS;
    float* v    = ws + OFF_V;
    int*   cnts = (int*)(ws + OFF_CNT);

    deg_hist_kernel<<<EBLK, HTHR, 0, stream>>>(dst, pdeg);

    reduce_deg_kernel<<<RB, 256, 0, stream>>>(pdeg, dinv, v, cnts);

    s_hist_kernel<<<EBLK, HTHR, 0, stream>>>(src, dst, dinv, ps);

    wsum_mlp_kernel<<<CHUNKS + 1, WTHR, 0, stream>>>(fa, fb, dinv, ps,
                                                     Wg, bg, W1, b1, W2, b2,
                                                     v, cnts, out);
}